// Round 12
// baseline (192.372 us; speedup 1.0000x reference)
//
#include <hip/hip_runtime.h>
#include <math.h>

#define NG 2048
#define NPG 64
#define EPG 512
#define ETOT (NG*EPG)
#define IND 64
#define H1D 128
#define H2D 64
#define OUTD 2016

typedef __attribute__((ext_vector_type(8))) short bf16x8;
typedef __attribute__((ext_vector_type(4))) float f32x4;

__device__ inline short f2b(float f) {
  union { float f; unsigned u; } v; v.f = f;
  unsigned r = (v.u + 0x7FFFu + ((v.u >> 16) & 1u)) >> 16;
  return (short)r;
}
__device__ inline unsigned pack2(short a, short b) {
  return (unsigned)(unsigned short)a | ((unsigned)(unsigned short)b << 16);
}

// ---- pre-kernel: W1 -> frag-sequential layout WTgF[((ct*4+ks)*64+l)*8+j]
__global__ void p_w1(const float* __restrict__ w1_rel, const float* __restrict__ w1_root,
                     short* __restrict__ WTgF) {
  const int ct = blockIdx.x;             // 0..7
  const int ks = threadIdx.x >> 6, l = threadIdx.x & 63;
  const int col = ct*16 + (l & 15);
  const int kb  = ks*32 + (l >> 4)*8;
  short tmp[8];
  #pragma unroll
  for (int j = 0; j < 8; ++j) {
    const int k = kb + j;
    float v = (k < 64) ? w1_rel[k*H1D + col] : w1_root[(k - 64)*H1D + col];
    tmp[j] = f2b(v);
  }
  *(uint4*)&WTgF[(size_t)((ct*4 + ks)*64 + l)*8] = *(uint4*)tmp;
}

// ================= Kernel 1: per-graph encoder (+ folded weight transforms) ==========
// LDS = 31744 B -> 5 blocks/CU, TWO barriers. All global inputs for the whole block
// (edges, x, 32 W1 B-frags, 8 biases) are prefetched at block start — the adjacency
// atomics + staging + barriers hide the entire load latency; phase 2 runs from regs.
__global__ __launch_bounds__(256, 5) void k1_encoder(
    const float* __restrict__ x, const int* __restrict__ ei,
    const short* __restrict__ WTgF, const float* __restrict__ b1,
    float* __restrict__ SVp,
    const float* __restrict__ fc2_w, const float* __restrict__ w2_rel, const float* __restrict__ w2_root,
    const float* __restrict__ w3_rel, const float* __restrict__ w3_root,
    const float* __restrict__ fc1_w,
    short* __restrict__ WF2g, short* __restrict__ W23T, short* __restrict__ fc1T)
{
  __shared__ __align__(16) char smem[32768];
  const int g = blockIdx.x;
  const int tid = threadIdx.x;

  if (g >= NG) {
    // ---------- folded transform path ----------
    float* L = (float*)smem;
    const int bid = g - NG;               // 0..68
    if (bid < 63) {                       // fc2 -> frag-sequential WF2g
      const int c0 = bid*32;
      for (int i = tid; i < 4096; i += 256) {
        int k = i >> 5, c = i & 31;
        L[k*33 + c] = fc2_w[(size_t)k*OUTD + c0 + c];
      }
      __syncthreads();
      const int tl = tid >> 7;
      const int r  = tid & 127;
      const int ks = r >> 5;
      const int lp = r & 31;
      const int ct = bid*2 + tl;
      #pragma unroll
      for (int u = 0; u < 2; ++u) {
        const int l = lp*2 + u;
        const int cl = tl*16 + (l & 15);
        const int kb = ks*32 + (l >> 4)*8;
        short tmp[8];
        #pragma unroll
        for (int j = 0; j < 8; ++j) tmp[j] = f2b(L[(kb + j)*33 + cl]);
        *(uint4*)&WF2g[(size_t)((ct*4 + ks)*64 + l)*8] = *(uint4*)tmp;
      }
    } else if (bid < 67) {                // w2/w3 -> W23T (pitch 264), two passes
      const int cc = bid - 63;
      const int j0 = cc*32;
      const float* wrel  = (cc < 2) ? w2_rel  : w3_rel;
      const float* wroot = (cc < 2) ? w2_root : w3_root;
      const int jl = j0 & 63;
      const int c = tid >> 3, k0 = (tid & 7)*32;
      for (int i = tid; i < 4096; i += 256) {
        int k = i >> 5, cc2 = i & 31;
        L[k*33 + cc2] = wrel[k*H2D + jl + cc2];
      }
      __syncthreads();
      if (k0 < 128)
        for (int kk = 0; kk < 32; ++kk)
          W23T[(size_t)(j0 + c)*264 + k0 + kk] = f2b(L[(k0 + kk)*33 + c]);
      __syncthreads();
      for (int i = tid; i < 4096; i += 256) {
        int k = i >> 5, cc2 = i & 31;
        L[k*33 + cc2] = wroot[k*H2D + jl + cc2];
      }
      __syncthreads();
      if (k0 >= 128)
        for (int kk = 0; kk < 32; ++kk)
          W23T[(size_t)(j0 + c)*264 + k0 + kk] = f2b(L[(k0 + kk - 128)*33 + c]);
    } else {                              // fc1 -> fc1T (pitch 72)
      const int c0 = (bid - 67)*64;
      for (int i = tid; i < 4096; i += 256) {
        int k = i >> 6, c = i & 63;
        L[k*65 + c] = fc1_w[k*H1D + c0 + c];
      }
      __syncthreads();
      const int c = tid >> 2, k0 = (tid & 3)*16;
      for (int kk = 0; kk < 16; ++kk)
        fc1T[(size_t)(c0 + c)*72 + k0 + kk] = f2b(L[(k0 + kk)*65 + c]);
    }
    return;
  }

  // ---------- encoder path ----------
  short* Xb   = (short*)smem;               // 9216
  short* XbT  = (short*)(smem + 9216);      // 9216
  short* Ab   = (short*)(smem + 18432);     // 9216 (->AGb overlay, wave-local rows)
  unsigned* Au32 = (unsigned*)(smem + 27648); // 4096 (packed u8 counts)

  const int w = tid >> 6, l = tid & 63;
  const int fr = l & 15;
  const int koff = (l >> 4) * 8;

  // ======== prefetch burst: ALL global inputs for this block ========
  const int e0 = g*EPG + tid*2;
  const int s0 = ei[e0] & 63,     d0 = ei[ETOT + e0] & 63;
  const int s1 = ei[e0 + 1] & 63, d1 = ei[ETOT + e0 + 1] & 63;

  const int p2 = tid >> 3;                 // node pair: nodes 2p2, 2p2+1 (wave-local rows)
  const int f0 = (tid & 7) * 8;            // features f0..f0+7
  const float* xr0 = x + (size_t)g*(NPG*IND) + (2*p2)*IND + f0;
  const float* xr1 = xr0 + IND;
  float4 u0 = *(const float4*)&xr0[0];
  float4 u1 = *(const float4*)&xr0[4];
  float4 u2 = *(const float4*)&xr1[0];
  float4 u3 = *(const float4*)&xr1[4];

  bf16x8 wfr[32];                          // entire phase-2 B-operand (128 VGPRs)
  #pragma unroll
  for (int t8 = 0; t8 < 8; ++t8)
    #pragma unroll
    for (int ks = 0; ks < 4; ++ks)
      wfr[t8*4 + ks] = *(const bf16x8*)&WTgF[(size_t)((t8*4 + ks)*64 + l)*8];

  float bbv[8];
  #pragma unroll
  for (int t8 = 0; t8 < 8; ++t8) bbv[t8] = b1[t8*16 + fr];
  // ==================================================================

  for (int i = tid; i < 64*16; i += 256) Au32[i] = 0u;
  __syncthreads();                        // b1: Au32 zeroed -> atomics

  // adjacency: packed u8 counts (4 cells per u32, pitch 16 words)
  atomicAdd(&Au32[d0*16 + (s0 >> 2)], 1u << (8*(s0 & 3)));
  atomicAdd(&Au32[d1*16 + (s1 >> 2)], 1u << (8*(s1 & 3)));

  // stage Xb (row-major bf16, b128 writes) + XbT (transposed, paired b32 writes)
  {
    short a[8], b[8];
    a[0]=f2b(u0.x); a[1]=f2b(u0.y); a[2]=f2b(u0.z); a[3]=f2b(u0.w);
    a[4]=f2b(u1.x); a[5]=f2b(u1.y); a[6]=f2b(u1.z); a[7]=f2b(u1.w);
    b[0]=f2b(u2.x); b[1]=f2b(u2.y); b[2]=f2b(u2.z); b[3]=f2b(u2.w);
    b[4]=f2b(u3.x); b[5]=f2b(u3.y); b[6]=f2b(u3.z); b[7]=f2b(u3.w);
    *(uint4*)&Xb[(2*p2)*72 + f0]     = *(uint4*)a;
    *(uint4*)&Xb[(2*p2 + 1)*72 + f0] = *(uint4*)b;
    unsigned* xt = (unsigned*)&XbT[f0*72 + 2*p2];
    #pragma unroll
    for (int j = 0; j < 8; ++j)
      *(unsigned*)((char*)xt + j*144) = pack2(a[j], b[j]);
  }
  __syncthreads();                        // b2: atomics + staging -> everything below

  // cvt u8 -> bf16 into Ab; rows WAVE-LOCAL (wave w owns rows 16w..16w+15)
  {
    const int row = tid >> 2, qw = tid & 3;
    unsigned wds[4];
    #pragma unroll
    for (int q = 0; q < 4; ++q) wds[q] = Au32[row*16 + qw*4 + q];
    unsigned* abp = (unsigned*)&Ab[row*72 + qw*16];
    #pragma unroll
    for (int q = 0; q < 4; ++q) {
      unsigned wv = wds[q];
      #pragma unroll
      for (int p = 0; p < 2; ++p) {
        unsigned c0 = (wv >> (16*p)) & 255u, c1 = (wv >> (16*p + 8)) & 255u;
        abp[q*2 + p] = pack2(f2b((float)c0), f2b((float)c1));
      }
    }
  }

  // deg per-wave in registers (SWAR shfl-reduce over Au32)
  float dg[4];
  {
    unsigned ps = 0;
    #pragma unroll
    for (int i = 0; i < 4; ++i) ps += Au32[((l >> 2) + 16*i)*16 + 4*w + (l & 3)];
    ps += __shfl_xor(ps, 4);
    ps += __shfl_xor(ps, 8);
    ps += __shfl_xor(ps, 16);
    ps += __shfl_xor(ps, 32);
    unsigned dword = __shfl(ps, (l >> 4));
    dg[0] = (float)(dword & 255u);
    dg[1] = (float)((dword >> 8) & 255u);
    dg[2] = (float)((dword >> 16) & 255u);
    dg[3] = (float)(dword >> 24);
  }

  const int rm = w*16;

  // phase 1: AG = A @ X — Ab rows own-wave, XbT all-waves (b2-covered)
  f32x4 agc[4];
  #pragma unroll
  for (int t = 0; t < 4; ++t) agc[t] = (f32x4){0.f,0.f,0.f,0.f};
  #pragma unroll
  for (int ks = 0; ks < 2; ++ks) {
    bf16x8 a = *(const bf16x8*)&Ab[(rm + fr)*72 + ks*32 + koff];
    #pragma unroll
    for (int t = 0; t < 4; ++t) {
      bf16x8 b = *(const bf16x8*)&XbT[(t*16 + fr)*72 + ks*32 + koff];
      agc[t] = __builtin_amdgcn_mfma_f32_16x16x32_bf16(a, b, agc[t], 0, 0, 0);
    }
  }
  // overlay: write AG bf16 over own Ab rows (same-wave reads already consumed them)
  short* AGb = Ab;
  #pragma unroll
  for (int t = 0; t < 4; ++t)
    #pragma unroll
    for (int r = 0; r < 4; ++r)
      AGb[(rm + (l>>4)*4 + r)*72 + t*16 + fr] = f2b(agc[t][r]);
  // NO barrier: phase 2 consumes only own-wave AGb/Xb rows + registers.

  // phase 2: h1pre = [AG|X] @ W1 — B-operand already in registers (wfr)
  {
    bf16x8 afr[4];
    #pragma unroll
    for (int ks = 0; ks < 4; ++ks)
      afr[ks] = (ks < 2)
        ? *(const bf16x8*)&AGb[(rm + fr)*72 + ks*32 + koff]
        : *(const bf16x8*)&Xb[(rm + fr)*72 + (ks-2)*32 + koff];

    f32x4 acc[8];
    #pragma unroll
    for (int t = 0; t < 8; ++t) acc[t] = (f32x4){0.f,0.f,0.f,0.f};
    #pragma unroll
    for (int t = 0; t < 8; ++t)
      #pragma unroll
      for (int ks = 0; ks < 4; ++ks)
        acc[t] = __builtin_amdgcn_mfma_f32_16x16x32_bf16(afr[ks], wfr[t*4 + ks], acc[t], 0, 0, 0);

    // epilogue: per-wave partial colsums straight to global (no LDS, no barrier)
    float* SVp_g = SVp + (size_t)(g*4 + w)*256;
    #pragma unroll
    for (int t = 0; t < 8; ++t) {
      const int col = t*16 + fr;
      const float bb = bbv[t];
      float hs = 0.f, ws = 0.f;
      #pragma unroll
      for (int r = 0; r < 4; ++r) {
        float v = fmaxf(acc[t][r] + bb, 0.f);
        hs += v; ws += dg[r]*v;
      }
      hs += __shfl_down(hs, 32); ws += __shfl_down(ws, 32);
      hs += __shfl_down(hs, 16); ws += __shfl_down(ws, 16);
      if (l < 16) {
        SVp_g[col]       = ws;
        SVp_g[128 + col] = hs;
      }
    }
  }
}

// ================= Kernel 1b: batched conv2/3-mean + reparam + fc1 ==========
__global__ __launch_bounds__(256) void k1b_latent(
    const float* __restrict__ SVp, const short* __restrict__ W23T,
    const float* __restrict__ b2, const float* __restrict__ b3,
    const float* __restrict__ eps, const short* __restrict__ fc1T,
    const float* __restrict__ fc1_b,
    float* __restrict__ out_mu, float* __restrict__ out_lv, short* __restrict__ hbufF)
{
  __shared__ short SV[32*264];
  __shared__ short Zt[32*72];
  const int g0 = blockIdx.x * 32;
  const int tid = threadIdx.x;
  const int w = tid >> 6, l = tid & 63;
  const int s = w >> 1;
  const int h = w & 1;
  const int fr = l & 15;
  const int koff = (l >> 4) * 8;

  // stage SV tile: sum 4 per-wave partials (coalesced fp32 loads)
  for (int i = tid; i < 32*256; i += 256) {
    const int r = i >> 8, k = i & 255;
    const float* p4 = SVp + (size_t)(g0 + r)*1024 + k;
    float v = (p4[0] + p4[256]) + (p4[512] + p4[768]);
    SV[r*264 + k] = f2b(v);
  }
  __syncthreads();

  f32x4 acc[4];
  #pragma unroll
  for (int t = 0; t < 4; ++t) acc[t] = (f32x4){0.f,0.f,0.f,0.f};
  #pragma unroll
  for (int ks = 0; ks < 8; ++ks) {
    bf16x8 a = *(const bf16x8*)&SV[(s*16 + fr)*264 + ks*32 + koff];
    #pragma unroll
    for (int j = 0; j < 2; ++j) {
      bf16x8 bm = *(const bf16x8*)&W23T[((2*h + j)*16 + fr)*264 + ks*32 + koff];
      bf16x8 bl = *(const bf16x8*)&W23T[((2*h + j + 4)*16 + fr)*264 + ks*32 + koff];
      acc[j]     = __builtin_amdgcn_mfma_f32_16x16x32_bf16(a, bm, acc[j], 0, 0, 0);
      acc[2 + j] = __builtin_amdgcn_mfma_f32_16x16x32_bf16(a, bl, acc[2 + j], 0, 0, 0);
    }
  }
  #pragma unroll
  for (int j = 0; j < 2; ++j) {
    const int col = (2*h + j)*16 + fr;
    const float bb2 = b2[col], bb3 = b3[col];
    #pragma unroll
    for (int r = 0; r < 4; ++r) {
      const int row = s*16 + (l>>4)*4 + r;
      const size_t gg = (size_t)(g0 + row);
      float mu = acc[j][r]     * (1.f/64.f) + bb2;
      float lv = acc[2 + j][r] * (1.f/64.f) + bb3;
      out_mu[gg*64 + col] = mu;
      out_lv[gg*64 + col] = lv;
      float z = mu + eps[gg*64 + col] * __expf(0.5f*lv);
      Zt[row*72 + col] = f2b(z);
    }
  }
  __syncthreads();

  f32x4 hacc[4];
  #pragma unroll
  for (int t = 0; t < 4; ++t) hacc[t] = (f32x4){0.f,0.f,0.f,0.f};
  #pragma unroll
  for (int ks = 0; ks < 2; ++ks) {
    bf16x8 a = *(const bf16x8*)&Zt[(s*16 + fr)*72 + ks*32 + koff];
    #pragma unroll
    for (int j = 0; j < 4; ++j) {
      bf16x8 b = *(const bf16x8*)&fc1T[((h*4 + j)*16 + fr)*72 + ks*32 + koff];
      hacc[j] = __builtin_amdgcn_mfma_f32_16x16x32_bf16(a, b, hacc[j], 0, 0, 0);
    }
  }
  // scatter into A-frag-sequential layout for k2
  #pragma unroll
  for (int j = 0; j < 4; ++j) {
    const int col = (h*4 + j)*16 + fr;      // 0..127
    const int ks  = col >> 5;
    const int q   = (col >> 3) & 3;
    const int j8  = col & 7;
    const float bb = fc1_b[col];
    #pragma unroll
    for (int r = 0; r < 4; ++r) {
      const int row = s*16 + (l>>4)*4 + r;  // 0..31
      const int rt  = blockIdx.x*2 + (row >> 4);
      const int lane = (row & 15) + 16*q;
      hbufF[(size_t)((rt*4 + ks)*64 + lane)*8 + j8] = f2b(fmaxf(hacc[j][r] + bb, 0.f));
    }
  }
}

// ================= Kernel 2: decoder GEMM — zero LDS, zero barriers ==========
__global__ __launch_bounds__(256, 8) void k2_decoder(
    const short* __restrict__ hbufF, const short* __restrict__ WF2g,
    const float* __restrict__ fc2_b, float* __restrict__ recon)
{
  const int bx = blockIdx.x, by = blockIdx.y;
  const int tid = threadIdx.x;
  const int w = tid >> 6, l = tid & 63;
  const int fr = l & 15;
  const int rt = bx*4 + w;                 // row-tile (16 rows)

  bf16x8 afr[4];
  #pragma unroll
  for (int ks = 0; ks < 4; ++ks)
    afr[ks] = *(const bf16x8*)&hbufF[(size_t)((rt*4 + ks)*64 + l)*8];

  f32x4 acc[6];
  #pragma unroll
  for (int t = 0; t < 6; ++t) acc[t] = (f32x4){0.f,0.f,0.f,0.f};

  #pragma unroll
  for (int ks = 0; ks < 4; ++ks) {
    #pragma unroll
    for (int t = 0; t < 6; ++t) {
      const int ct = by*6 + t;
      bf16x8 b = *(const bf16x8*)&WF2g[(size_t)((ct*4 + ks)*64 + l)*8];
      acc[t] = __builtin_amdgcn_mfma_f32_16x16x32_bf16(afr[ks], b, acc[t], 0, 0, 0);
    }
  }

  #pragma unroll
  for (int t = 0; t < 6; ++t) {
    const int col = by*96 + t*16 + fr;
    const float bb = fc2_b[col];
    #pragma unroll
    for (int r = 0; r < 4; ++r) {
      const int row = bx*64 + w*16 + (l>>4)*4 + r;
      float v = acc[t][r] + bb;
      recon[(size_t)row*OUTD + col] = 1.f/(1.f + __expf(-v));
    }
  }
}

extern "C" void kernel_launch(void* const* d_in, const int* in_sizes, int n_in,
                              void* d_out, int out_size, void* d_ws, size_t ws_size,
                              hipStream_t stream) {
  const float* x       = (const float*)d_in[0];
  const int*   ei      = (const int*)d_in[1];
  const float* eps     = (const float*)d_in[3];
  const float* w1_rel  = (const float*)d_in[4];
  const float* b1      = (const float*)d_in[5];
  const float* w1_root = (const float*)d_in[6];
  const float* w2_rel  = (const float*)d_in[7];
  const float* b2      = (const float*)d_in[8];
  const float* w2_root = (const float*)d_in[9];
  const float* w3_rel  = (const float*)d_in[10];
  const float* b3      = (const float*)d_in[11];
  const float* w3_root = (const float*)d_in[12];
  const float* fc1_w   = (const float*)d_in[13];
  const float* fc1_b   = (const float*)d_in[14];
  const float* fc2_w   = (const float*)d_in[15];
  const float* fc2_b   = (const float*)d_in[16];

  float* recon  = (float*)d_out;
  float* out_mu = recon + (size_t)NG*OUTD;
  float* out_lv = out_mu + (size_t)NG*H2D;

  char* p = (char*)d_ws;
  short* WTgF  = (short*)p;              p += 8*4*64*8*2;           // 32768
  short* WF2g  = (short*)p;              p += 126*4*64*8*2;         // 516096
  short* fc1T  = (short*)p;              p += 128*72*2;             // 18432
  short* W23T  = (short*)p;              p += 128*264*2;            // 67584
  float* SVp   = (float*)p;              p += (size_t)NG*4*256*4;   // 8 MB
  short* hbufF = (short*)p;                                          // 524288

  p_w1<<<8, 256, 0, stream>>>(w1_rel, w1_root, WTgF);
  k1_encoder<<<NG + 69, 256, 0, stream>>>(x, ei, WTgF, b1, SVp,
      fc2_w, w2_rel, w2_root, w3_rel, w3_root, fc1_w, WF2g, W23T, fc1T);
  k1b_latent<<<64, 256, 0, stream>>>(SVp, W23T, b2, b3, eps, fc1T, fc1_b,
                                     out_mu, out_lv, hbufF);
  k2_decoder<<<dim3(32, 21), 256, 0, stream>>>(hbufF, WF2g, fc2_b, recon);
}